// Round 2
// baseline (155.108 us; speedup 1.0000x reference)
//
#include <hip/hip_runtime.h>

// Problem constants (from reference)
#define NQ    10
#define DIM   1024        // 2^NQ
#define N_CLS 10
#define NROWS 16384
#define IMG   784

#define ROWS_PER_BLK  8   // rows handled per block (sequentially)
#define WAVES_PER_BLK 4   // 256 threads; wave w owns cols [256w, 256w+256)

// ---------------------------------------------------------------------------
// Wave64 sum via DPP. Result valid in lane 63. VALU pipe only (no LDS).
// ---------------------------------------------------------------------------
__device__ __forceinline__ float wave64_sum(float x) {
#define DPP_ADD(ctrl, rmask, bmask)                                           \
  x += __int_as_float(__builtin_amdgcn_update_dpp(                            \
      0, __float_as_int(x), ctrl, rmask, bmask, true));
  DPP_ADD(0x111, 0xf, 0xf)  // row_shr:1
  DPP_ADD(0x112, 0xf, 0xf)  // row_shr:2
  DPP_ADD(0x114, 0xf, 0xe)  // row_shr:4
  DPP_ADD(0x118, 0xf, 0xc)  // row_shr:8
  DPP_ADD(0x142, 0xa, 0xf)  // row_bcast:15
  DPP_ADD(0x143, 0xc, 0xf)  // row_bcast:31
#undef DPP_ADD
  return x;  // total in lane 63
}

// ---------------------------------------------------------------------------
// Kernel 1: ref[c][d] = canon[c][d] / ||canon[c]|| for d<784, else 0.
// ---------------------------------------------------------------------------
__global__ void ref_prep_kernel(const float* __restrict__ canon,
                                float* __restrict__ ref) {
  __shared__ float red[256];
  const int c = blockIdx.x;
  const int t = threadIdx.x;
  const float* src = canon + c * IMG;

  float ss = 0.f;
  for (int d = t; d < IMG; d += 256) {
    float v = src[d];
    ss += v * v;
  }
  red[t] = ss;
  __syncthreads();
  for (int s = 128; s > 0; s >>= 1) {
    if (t < s) red[t] += red[t + s];
    __syncthreads();
  }
  const float inv = 1.0f / sqrtf(red[0]);

  for (int d = t; d < DIM; d += 256) {
    ref[c * DIM + d] = (d < IMG) ? src[d] * inv : 0.f;
  }
}

// ---------------------------------------------------------------------------
// Kernel 2: 2048 blocks x 256 threads (4 waves). Wave w owns columns
// [256w, 256w+256); lane owns 4 contiguous cols -> per-lane ref fragment is
// 10 x float4 = 40 VGPRs (ACTUALLY fits in registers this time; total ~105
// VGPR under __launch_bounds__(256,4) -> 16 waves/CU resident).
// Per row: 2 coalesced dwordx4 z loads (next row prefetched), 80 FMAs,
// 6-step DPP reduce of 20 partials, 320 B LDS cross-wave combine.
// ---------------------------------------------------------------------------
__global__ __launch_bounds__(256, 4) void swaptest_kernel(
    const float* __restrict__ zre, const float* __restrict__ zim,
    const float* __restrict__ ref, float* __restrict__ out) {
  __shared__ float part[WAVES_PER_BLK][2 * N_CLS];

  const int tid = threadIdx.x;
  const int wave = tid >> 6;
  const int lane = tid & 63;
  const int colbase = wave * 256 + lane * 4;

  // ref fragment: rv[c] = ref[c][colbase .. colbase+3]  (40 VGPRs, L2-hot)
  float4 rv[N_CLS];
#pragma unroll
  for (int c = 0; c < N_CLS; ++c)
    rv[c] = *(const float4*)(ref + c * DIM + colbase);

  const int row0 = blockIdx.x * ROWS_PER_BLK;
  const float* pre = zre + (size_t)row0 * DIM + colbase;
  const float* pim = zim + (size_t)row0 * DIM + colbase;

  float4 cre = *(const float4*)pre;
  float4 cim = *(const float4*)pim;

  for (int r = 0; r < ROWS_PER_BLK; ++r) {
    // software prefetch of next row's fragment (issued before compute phase)
    float4 nre = cre, nim = cim;
    if (r + 1 < ROWS_PER_BLK) {
      nre = *(const float4*)(pre + (size_t)(r + 1) * DIM);
      nim = *(const float4*)(pim + (size_t)(r + 1) * DIM);
    }

    float acc[2 * N_CLS];
#pragma unroll
    for (int c = 0; c < N_CLS; ++c) {
      const float4 rvc = rv[c];
      acc[2 * c] =
          cre.x * rvc.x + cre.y * rvc.y + cre.z * rvc.z + cre.w * rvc.w;
      acc[2 * c + 1] =
          cim.x * rvc.x + cim.y * rvc.y + cim.z * rvc.z + cim.w * rvc.w;
    }

    // 64-lane reduction per partial; totals land in lane 63
#pragma unroll
    for (int v = 0; v < 2 * N_CLS; ++v) acc[v] = wave64_sum(acc[v]);

    if (lane == 63) {
#pragma unroll
      for (int v = 0; v < 2 * N_CLS; ++v) part[wave][v] = acc[v];
    }
    __syncthreads();

    if (tid < N_CLS) {
      float are = 0.f, aim = 0.f;
#pragma unroll
      for (int w = 0; w < WAVES_PER_BLK; ++w) {
        are += part[w][2 * tid];
        aim += part[w][2 * tid + 1];
      }
      out[(size_t)(row0 + r) * N_CLS + tid] = are * are + aim * aim;
    }
    __syncthreads();  // protect part[] reuse next row

    cre = nre;
    cim = nim;
  }
}

// ---------------------------------------------------------------------------
extern "C" void kernel_launch(void* const* d_in, const int* in_sizes, int n_in,
                              void* d_out, int out_size, void* d_ws,
                              size_t ws_size, hipStream_t stream) {
  const float* z_re = (const float*)d_in[0];
  const float* z_im = (const float*)d_in[1];
  const float* canon = (const float*)d_in[2];
  float* out = (float*)d_out;
  float* ref = (float*)d_ws;  // 10 * 1024 * 4 B = 40 KiB

  ref_prep_kernel<<<N_CLS, 256, 0, stream>>>(canon, ref);

  const int nblk = NROWS / ROWS_PER_BLK;  // 2048 blocks x 256 threads
  swaptest_kernel<<<nblk, 256, 0, stream>>>(z_re, z_im, ref, out);
}